// Round 3
// baseline (6604.811 us; speedup 1.0000x reference)
//
#include <hip/hip_runtime.h>
#include <math.h>

#define T_STEPS 1024
#define BATCH   512
#define DZ      256
#define DH      256
#define RANK    8
#define DY      16

// Block: 1024 threads = 16 waves, 2 batch elements for all T steps.
// Thread (i = tid&255, q = tid>>8): output-neuron i, k-quadrant q.
// Register-resident weights: W_zz[i,64q:64q+64], Wz_in[i,16q:16q+16], W_in[i,8q:8q+8].
//
// amdgpu_waves_per_eu(4,4): pin min=max=4 waves/EU so the allocator budget is
// 128 VGPR (R2 kept the default 8-waves/EU target -> 64-VGPR cap -> weights
// spilled to scratch: WRITE_SIZE 5.4GB vs 1.1GB true output).
// Launch adds 32KB dynamic LDS (total ~89KB > 80KB) so hardware can never
// co-schedule 2 blocks on one CU (grid == #CUs; stragglers otherwise).

__device__ __forceinline__ float fast_tanh(float x) {
    const float e = __expf(2.0f * x);          // v_exp_f32 path
    return 1.0f - 2.0f / (e + 1.0f);
}

__global__ __launch_bounds__(1024)
__attribute__((amdgpu_waves_per_eu(4, 4)))
void nmrnn_kernel(
    const float* __restrict__ s, const float* __restrict__ c,
    const float* __restrict__ W_zz, const float* __restrict__ Wz_in,
    const float* __restrict__ bz_in, const float* __restrict__ Wz_out,
    const float* __restrict__ bz_out, const float* __restrict__ U,
    const float* __restrict__ V, const float* __restrict__ W_in,
    const float* __restrict__ b_in, const float* __restrict__ W_out,
    const float* __restrict__ b_out,
    float* __restrict__ out, float* __restrict__ states)
{
    __shared__ float tz[2][DZ];        // tanh(z_{t-1}) -> tanh(z_t)
    __shared__ float th[2][DH];        // tanh(h_{t-1}) -> tanh(h_t)
    __shared__ float zl[2][DZ];        // z_t (for signal dot)
    __shared__ float red[4][2][256];   // cross-quadrant reduction scratch
    __shared__ float scl[2][64];       // [s_t | c_t] per batch element
    __shared__ float wzo[RANK][DZ];    // Wz_out (native layout [r][k])
    __shared__ float vt[RANK][DH];     // V transposed  -> vt[r][k]
    __shared__ float ut[RANK][DH];     // U transposed  -> ut[r][i]
    __shared__ float wo[DY][DH];       // W_out (native layout [y][k])
    __shared__ float gl[2][RANK];      // signal * (tanh(h) @ V)
    __shared__ float bzo[RANK];
    __shared__ float bo[DY];

    const int tid = threadIdx.x;
    const int i   = tid & 255;
    const int q   = tid >> 8;          // 0..3
    const int b0  = blockIdx.x * 2;

    // ---- register-resident weights ----
    float wzz[64];
    #pragma unroll
    for (int m = 0; m < 64; m += 4) {
        const float4 v4 = *reinterpret_cast<const float4*>(&W_zz[i * 256 + q * 64 + m]);
        wzz[m] = v4.x; wzz[m + 1] = v4.y; wzz[m + 2] = v4.z; wzz[m + 3] = v4.w;
    }
    float wzi[16];
    #pragma unroll
    for (int m = 0; m < 16; m += 4) {
        const float4 v4 = *reinterpret_cast<const float4*>(&Wz_in[i * 64 + q * 16 + m]);
        wzi[m] = v4.x; wzi[m + 1] = v4.y; wzi[m + 2] = v4.z; wzi[m + 3] = v4.w;
    }
    float wi[8];
    #pragma unroll
    for (int m = 0; m < 8; m += 4) {
        const float4 v4 = *reinterpret_cast<const float4*>(&W_in[i * 32 + q * 8 + m]);
        wi[m] = v4.x; wi[m + 1] = v4.y; wi[m + 2] = v4.z; wi[m + 3] = v4.w;
    }

    // ---- stage small matrices in LDS ----
    if (tid < 512) {  // Wz_out: 2048 floats
        const float4 v4 = *reinterpret_cast<const float4*>(&Wz_out[tid * 4]);
        *reinterpret_cast<float4*>(&((float*)wzo)[tid * 4]) = v4;
    }
    {   // W_out: 4096 floats
        const float4 v4 = *reinterpret_cast<const float4*>(&W_out[tid * 4]);
        *reinterpret_cast<float4*>(&((float*)wo)[tid * 4]) = v4;
    }
    if (tid < 256) {  // transpose V, U
        #pragma unroll
        for (int r = 0; r < RANK; ++r) vt[r][tid] = V[tid * RANK + r];
        #pragma unroll
        for (int r = 0; r < RANK; ++r) ut[r][tid] = U[tid * RANK + r];
    }
    if (tid < RANK) bzo[tid] = bz_out[tid];
    if (tid < DY)   bo[tid]  = b_out[tid];

    const float bzi_r = (tid < 512) ? bz_in[i] : 0.f;
    const float bi_r  = (tid < 512) ? b_in[i]  : 0.f;
    float z_r = 0.f, h_r = 0.f;

    // per-thread s/c source pointer (threads 0..127 stream the step inputs)
    const float* src = s;
    if (tid < 128) {
        const int b = tid >> 6, r = tid & 63;
        src = (r < 32) ? (s + (size_t)(b0 + b) * 32 + r)
                       : (c + (size_t)(b0 + b) * 32 + (r - 32));
    }
    float pf = (tid < 128) ? src[0] : 0.f;   // prefetch t=0

    // per-thread states pointer (threads 0..511 write z and h)
    float* stp = states + (size_t)(b0 + q) * 512 + i;

    if (tid < 512) {  // init (z0 = h0 = 0)
        tz[q][i] = 0.f; th[q][i] = 0.f; zl[q][i] = 0.f;
    }
    __syncthreads();

    for (int t = 0; t < T_STEPS; ++t) {
        // ---- phase 1: publish prefetched s_t, c_t ----
        if (tid < 128) scl[tid >> 6][tid & 63] = pf;
        __syncthreads();  // A
        // issue next step's input load; consumed at phase 1 of t+1 (hidden)
        if (tid < 128 && t + 1 < T_STEPS) pf = src[(size_t)(t + 1) * (BATCH * 32)];

        // ---- phase 13': out for step t-1 (th still = tanh(h_{t-1})) ----
        if (t > 0) {
            const int g = tid >> 6, l = tid & 63;
            float o0 = 0.f, o1 = 0.f;
            #pragma unroll
            for (int m = 0; m < 4; ++m) {
                const int k = l + 64 * m;
                const float w = wo[g][k];
                o0 = fmaf(th[0][k], w, o0);
                o1 = fmaf(th[1][k], w, o1);
            }
            #pragma unroll
            for (int off = 32; off >= 1; off >>= 1) {
                o0 += __shfl_xor(o0, off);
                o1 += __shfl_xor(o1, off);
            }
            if (l == 0) {
                out[((size_t)(t - 1) * BATCH + b0) * 16 + g]     = o0 + bo[g];
                out[((size_t)(t - 1) * BATCH + b0 + 1) * 16 + g] = o1 + bo[g];
            }
        }

        // ---- phase 3: z partial dots (W_zz quadrant + Wz_in) ----
        {
            float a0 = 0.f, a1 = 0.f;
            #pragma unroll
            for (int m = 0; m < 16; ++m) {
                const float4 t0 = *reinterpret_cast<const float4*>(&tz[0][(q << 6) + (m << 2)]);
                const float4 t1 = *reinterpret_cast<const float4*>(&tz[1][(q << 6) + (m << 2)]);
                a0 = fmaf(wzz[4 * m + 0], t0.x, a0);
                a0 = fmaf(wzz[4 * m + 1], t0.y, a0);
                a0 = fmaf(wzz[4 * m + 2], t0.z, a0);
                a0 = fmaf(wzz[4 * m + 3], t0.w, a0);
                a1 = fmaf(wzz[4 * m + 0], t1.x, a1);
                a1 = fmaf(wzz[4 * m + 1], t1.y, a1);
                a1 = fmaf(wzz[4 * m + 2], t1.z, a1);
                a1 = fmaf(wzz[4 * m + 3], t1.w, a1);
            }
            #pragma unroll
            for (int m = 0; m < 4; ++m) {
                const float4 s0 = *reinterpret_cast<const float4*>(&scl[0][(q << 4) + (m << 2)]);
                const float4 s1 = *reinterpret_cast<const float4*>(&scl[1][(q << 4) + (m << 2)]);
                a0 = fmaf(wzi[4 * m + 0], s0.x, a0);
                a0 = fmaf(wzi[4 * m + 1], s0.y, a0);
                a0 = fmaf(wzi[4 * m + 2], s0.z, a0);
                a0 = fmaf(wzi[4 * m + 3], s0.w, a0);
                a1 = fmaf(wzi[4 * m + 0], s1.x, a1);
                a1 = fmaf(wzi[4 * m + 1], s1.y, a1);
                a1 = fmaf(wzi[4 * m + 2], s1.z, a1);
                a1 = fmaf(wzi[4 * m + 3], s1.w, a1);
            }
            red[q][0][i] = a0;
            red[q][1][i] = a1;
        }
        __syncthreads();  // B

        // ---- phase 5: z update ----
        if (tid < 512) {
            const int b = q;
            const float tmp = red[0][b][i] + red[1][b][i] + red[2][b][i] + red[3][b][i] + bzi_r;
            z_r = 0.99f * z_r + 0.01f * tmp;
            zl[b][i] = z_r;
            tz[b][i] = fast_tanh(z_r);
            stp[(size_t)t * (BATCH * 512)] = z_r;
        }
        __syncthreads();  // C

        // ---- phase 7: signal & (tanh(h)@V) -> gl[b][r] ----
        {
            const int g = tid >> 6, l = tid & 63;
            const int b = g >> 3, r = g & 7;
            float zp = 0.f, hp = 0.f;
            #pragma unroll
            for (int m = 0; m < 4; ++m) {
                const int k = l + 64 * m;
                zp = fmaf(zl[b][k], wzo[r][k], zp);
                hp = fmaf(th[b][k], vt[r][k], hp);
            }
            #pragma unroll
            for (int off = 32; off >= 1; off >>= 1) {
                zp += __shfl_xor(zp, off);
                hp += __shfl_xor(hp, off);
            }
            if (l == 0) {
                const float sig = 1.f / (1.f + __expf(-(zp + bzo[r])));
                gl[b][r] = sig * hp;
            }
        }
        __syncthreads();  // D

        // ---- phase 9: h partial dots (U@g on q==0, W_in slice on all q) ----
        {
            float p0 = 0.f, p1 = 0.f;
            if (q == 0) {
                #pragma unroll
                for (int r = 0; r < RANK; ++r) {
                    const float u = ut[r][i];
                    p0 = fmaf(u, gl[0][r], p0);
                    p1 = fmaf(u, gl[1][r], p1);
                }
            }
            const float4 s0a = *reinterpret_cast<const float4*>(&scl[0][q * 8]);
            const float4 s0b = *reinterpret_cast<const float4*>(&scl[0][q * 8 + 4]);
            const float4 s1a = *reinterpret_cast<const float4*>(&scl[1][q * 8]);
            const float4 s1b = *reinterpret_cast<const float4*>(&scl[1][q * 8 + 4]);
            p0 = fmaf(wi[0], s0a.x, p0); p0 = fmaf(wi[1], s0a.y, p0);
            p0 = fmaf(wi[2], s0a.z, p0); p0 = fmaf(wi[3], s0a.w, p0);
            p0 = fmaf(wi[4], s0b.x, p0); p0 = fmaf(wi[5], s0b.y, p0);
            p0 = fmaf(wi[6], s0b.z, p0); p0 = fmaf(wi[7], s0b.w, p0);
            p1 = fmaf(wi[0], s1a.x, p1); p1 = fmaf(wi[1], s1a.y, p1);
            p1 = fmaf(wi[2], s1a.z, p1); p1 = fmaf(wi[3], s1a.w, p1);
            p1 = fmaf(wi[4], s1b.x, p1); p1 = fmaf(wi[5], s1b.y, p1);
            p1 = fmaf(wi[6], s1b.z, p1); p1 = fmaf(wi[7], s1b.w, p1);
            red[q][0][i] = p0;
            red[q][1][i] = p1;
        }
        __syncthreads();  // E

        // ---- phase 11: h update ----
        if (tid < 512) {
            const int b = q;
            const float tmp = red[0][b][i] + red[1][b][i] + red[2][b][i] + red[3][b][i] + bi_r;
            h_r = 0.9f * h_r + 0.1f * tmp;
            th[b][i] = fast_tanh(h_r);
            stp[(size_t)t * (BATCH * 512) + 256] = h_r;
        }
        // no barrier: next-iter phase 1 writes scl (disjoint); barrier A orders
        // th for phase 13' of the next iteration.
    }

    // ---- final out (t = T_STEPS-1) ----
    __syncthreads();
    {
        const int g = tid >> 6, l = tid & 63;
        float o0 = 0.f, o1 = 0.f;
        #pragma unroll
        for (int m = 0; m < 4; ++m) {
            const int k = l + 64 * m;
            const float w = wo[g][k];
            o0 = fmaf(th[0][k], w, o0);
            o1 = fmaf(th[1][k], w, o1);
        }
        #pragma unroll
        for (int off = 32; off >= 1; off >>= 1) {
            o0 += __shfl_xor(o0, off);
            o1 += __shfl_xor(o1, off);
        }
        if (l == 0) {
            out[((size_t)(T_STEPS - 1) * BATCH + b0) * 16 + g]     = o0 + bo[g];
            out[((size_t)(T_STEPS - 1) * BATCH + b0 + 1) * 16 + g] = o1 + bo[g];
        }
    }
}

extern "C" void kernel_launch(void* const* d_in, const int* in_sizes, int n_in,
                              void* d_out, int out_size, void* d_ws, size_t ws_size,
                              hipStream_t stream) {
    const float* s     = (const float*)d_in[0];
    const float* c     = (const float*)d_in[1];
    const float* W_zz  = (const float*)d_in[2];
    const float* Wz_in = (const float*)d_in[3];
    const float* bz_in = (const float*)d_in[4];
    const float* Wz_out= (const float*)d_in[5];
    const float* bz_out= (const float*)d_in[6];
    const float* U     = (const float*)d_in[7];
    const float* V     = (const float*)d_in[8];
    const float* W_in  = (const float*)d_in[9];
    const float* b_in  = (const float*)d_in[10];
    const float* W_out = (const float*)d_in[11];
    const float* b_out = (const float*)d_in[12];

    float* out    = (float*)d_out;
    float* states = out + (size_t)T_STEPS * BATCH * DY;

    // +32KB dynamic LDS: total group segment ~89KB -> hardware can only place
    // one block per CU (grid == 256 == #CUs), preventing 2-block stragglers.
    hipLaunchKernelGGL(nmrnn_kernel, dim3(BATCH / 2), dim3(1024), 32768, stream,
                       s, c, W_zz, Wz_in, bz_in, Wz_out, bz_out, U, V,
                       W_in, b_in, W_out, b_out, out, states);
}

// Round 4
// 3163.562 us; speedup vs baseline: 2.0878x; 2.0878x over previous
//
#include <hip/hip_runtime.h>
#include <math.h>

#define T_STEPS 1024
#define BATCH   512
#define DZ      256
#define DH      256
#define RANK    8
#define DY      16

// Block: 1024 threads = 16 waves, 2 batch elements for all T steps.
// Thread (i = tid&255, q = tid>>8): output-neuron i, k-quadrant q.
//
// R1-R3 lesson: the compiler pins VGPR budget at 64 (8 waves/EU target) and
// spilled the f32 register-resident weights (WRITE_SIZE 3-5 GB of scratch
// churn). This version fits the budget BY CONSTRUCTION: weights live as
// f16 pairs (W_zz slice = 32 VGPRs, Wz_in = 8, W_in = 4) consumed by
// v_dot2_f32_f16 (f32 accumulate; halves the phase-3 instruction stream).
// tanh(z) and [s|c] are f16-packed in LDS; phase-3 reads of them are
// wave-uniform broadcasts (conflict-free). Static LDS is pushed to ~82 KB
// (>80 KB) so hardware fits exactly 1 WG/CU and the compiler's LDS-derived
// occupancy target becomes 4 waves/EU (VGPR budget 128).

typedef _Float16 h2 __attribute__((ext_vector_type(2)));

__device__ __forceinline__ h2 pack2(float a, float b) {
    h2 r; r.x = (_Float16)a; r.y = (_Float16)b; return r;
}
__device__ __forceinline__ h2 bc(unsigned u) { return __builtin_bit_cast(h2, u); }

__device__ __forceinline__ float dot2(h2 a, h2 b, float c) {
#if __has_builtin(__builtin_amdgcn_fdot2)
    return __builtin_amdgcn_fdot2(a, b, c, false);
#else
    return fmaf((float)a.x, (float)b.x, fmaf((float)a.y, (float)b.y, c));
#endif
}

__device__ __forceinline__ float fast_tanh(float x) {
    const float e = __expf(2.0f * x);          // v_exp_f32 path
    return 1.0f - 2.0f / (e + 1.0f);
}

__global__ __launch_bounds__(1024, 4)
void nmrnn_kernel(
    const float* __restrict__ s, const float* __restrict__ c,
    const float* __restrict__ W_zz, const float* __restrict__ Wz_in,
    const float* __restrict__ bz_in, const float* __restrict__ Wz_out,
    const float* __restrict__ bz_out, const float* __restrict__ U,
    const float* __restrict__ V, const float* __restrict__ W_in,
    const float* __restrict__ b_in, const float* __restrict__ W_out,
    const float* __restrict__ b_out,
    float* __restrict__ out, float* __restrict__ states)
{
    __shared__ __align__(16) _Float16 tzh[2][DZ];   // tanh(z) packed f16
    __shared__ __align__(16) _Float16 sclh[2][64];  // [s_t|c_t] packed f16
    __shared__ __align__(16) float th[2][DH];       // tanh(h) f32
    __shared__ __align__(16) float zl[2][DZ];       // z_t f32 (signal dot)
    __shared__ __align__(16) float red[4][2][1152]; // reduction scratch; only
                                                    // [..][..][0..255] used —
                                                    // oversized to push static
                                                    // LDS past 80 KB (see top)
    __shared__ __align__(16) float wzo[RANK][DZ];   // Wz_out [r][k]
    __shared__ __align__(16) float vt[RANK][DH];    // V^T  [r][k]
    __shared__ __align__(16) float ut[RANK][DH];    // U^T  [r][i]
    __shared__ __align__(16) float wo[DY][DH];      // W_out [y][k]
    __shared__ float gl[2][RANK];                   // signal * (tanh(h) @ V)
    __shared__ float bzo[RANK];
    __shared__ float bo[DY];

    const int tid = threadIdx.x;
    const int i   = tid & 255;
    const int q   = tid >> 8;          // 0..3
    const int b0  = blockIdx.x * 2;

    // ---- register-resident f16-packed weights ----
    h2 wzzp[32];
    #pragma unroll
    for (int m = 0; m < 16; ++m) {
        const float4 v4 = *reinterpret_cast<const float4*>(&W_zz[i * 256 + (q << 6) + (m << 2)]);
        wzzp[2 * m]     = pack2(v4.x, v4.y);
        wzzp[2 * m + 1] = pack2(v4.z, v4.w);
    }
    h2 wzip[8];
    #pragma unroll
    for (int m = 0; m < 4; ++m) {
        const float4 v4 = *reinterpret_cast<const float4*>(&Wz_in[i * 64 + (q << 4) + (m << 2)]);
        wzip[2 * m]     = pack2(v4.x, v4.y);
        wzip[2 * m + 1] = pack2(v4.z, v4.w);
    }
    h2 wip[4];
    #pragma unroll
    for (int m = 0; m < 2; ++m) {
        const float4 v4 = *reinterpret_cast<const float4*>(&W_in[i * 32 + (q << 3) + (m << 2)]);
        wip[2 * m]     = pack2(v4.x, v4.y);
        wip[2 * m + 1] = pack2(v4.z, v4.w);
    }

    // ---- stage small f32 matrices in LDS ----
    if (tid < 512) {  // Wz_out: 2048 floats
        const float4 v4 = *reinterpret_cast<const float4*>(&Wz_out[tid * 4]);
        *reinterpret_cast<float4*>(&((float*)wzo)[tid * 4]) = v4;
    }
    {   // W_out: 4096 floats
        const float4 v4 = *reinterpret_cast<const float4*>(&W_out[tid * 4]);
        *reinterpret_cast<float4*>(&((float*)wo)[tid * 4]) = v4;
    }
    if (tid < 256) {  // transpose V, U
        #pragma unroll
        for (int r = 0; r < RANK; ++r) vt[r][tid] = V[tid * RANK + r];
        #pragma unroll
        for (int r = 0; r < RANK; ++r) ut[r][tid] = U[tid * RANK + r];
    }
    if (tid < RANK) bzo[tid] = bz_out[tid];
    if (tid < DY)   bo[tid]  = b_out[tid];

    const float bzi_r = (tid < 512) ? bz_in[i] : 0.f;
    const float bi_r  = (tid < 512) ? b_in[i]  : 0.f;
    float z_r = 0.f, h_r = 0.f;

    // threads 0..127 stream the step inputs (one scalar each)
    const float* src = s;
    if (tid < 128) {
        const int b = tid >> 6, r = tid & 63;
        src = (r < 32) ? (s + (size_t)(b0 + b) * 32 + r)
                       : (c + (size_t)(b0 + b) * 32 + (r - 32));
    }
    float pf = (tid < 128) ? src[0] : 0.f;   // prefetch t=0

    float* stp = states + (size_t)(b0 + q) * 512 + i;  // valid for tid<512

    if (tid < 512) {  // init (z0 = h0 = 0)
        tzh[q][i] = (_Float16)0.f; th[q][i] = 0.f; zl[q][i] = 0.f;
    }
    __syncthreads();

    for (int t = 0; t < T_STEPS; ++t) {
        // ---- phase 1: publish prefetched s_t, c_t (packed f16) ----
        if (tid < 128) sclh[tid >> 6][tid & 63] = (_Float16)pf;
        __syncthreads();  // A
        // issue next step's input load (latency hidden under this step)
        if (tid < 128 && t + 1 < T_STEPS) pf = src[(size_t)(t + 1) * (BATCH * 32)];

        // ---- phase 13': out for step t-1 (th still = tanh(h_{t-1})) ----
        if (t > 0) {
            const int g = tid >> 6, l = tid & 63;
            float o0 = 0.f, o1 = 0.f;
            #pragma unroll
            for (int m = 0; m < 4; ++m) {
                const int k = l + 64 * m;
                const float w = wo[g][k];
                o0 = fmaf(th[0][k], w, o0);
                o1 = fmaf(th[1][k], w, o1);
            }
            #pragma unroll
            for (int off = 32; off >= 1; off >>= 1) {
                o0 += __shfl_xor(o0, off);
                o1 += __shfl_xor(o1, off);
            }
            if (l == 0) {
                out[((size_t)(t - 1) * BATCH + b0) * 16 + g]     = o0 + bo[g];
                out[((size_t)(t - 1) * BATCH + b0 + 1) * 16 + g] = o1 + bo[g];
            }
        }

        // ---- phase 3: z partial dots via v_dot2 (uniform LDS broadcasts) ----
        {
            float a0 = 0.f, a1 = 0.f;
            const uint4* t0p = reinterpret_cast<const uint4*>(&tzh[0][q << 6]);
            const uint4* t1p = reinterpret_cast<const uint4*>(&tzh[1][q << 6]);
            #pragma unroll
            for (int m = 0; m < 8; ++m) {
                const uint4 u0 = t0p[m];
                const uint4 u1 = t1p[m];
                a0 = dot2(wzzp[4 * m + 0], bc(u0.x), a0);
                a0 = dot2(wzzp[4 * m + 1], bc(u0.y), a0);
                a0 = dot2(wzzp[4 * m + 2], bc(u0.z), a0);
                a0 = dot2(wzzp[4 * m + 3], bc(u0.w), a0);
                a1 = dot2(wzzp[4 * m + 0], bc(u1.x), a1);
                a1 = dot2(wzzp[4 * m + 1], bc(u1.y), a1);
                a1 = dot2(wzzp[4 * m + 2], bc(u1.z), a1);
                a1 = dot2(wzzp[4 * m + 3], bc(u1.w), a1);
            }
            const uint4* s0p = reinterpret_cast<const uint4*>(&sclh[0][q << 4]);
            const uint4* s1p = reinterpret_cast<const uint4*>(&sclh[1][q << 4]);
            #pragma unroll
            for (int m = 0; m < 2; ++m) {
                const uint4 u0 = s0p[m];
                const uint4 u1 = s1p[m];
                a0 = dot2(wzip[4 * m + 0], bc(u0.x), a0);
                a0 = dot2(wzip[4 * m + 1], bc(u0.y), a0);
                a0 = dot2(wzip[4 * m + 2], bc(u0.z), a0);
                a0 = dot2(wzip[4 * m + 3], bc(u0.w), a0);
                a1 = dot2(wzip[4 * m + 0], bc(u1.x), a1);
                a1 = dot2(wzip[4 * m + 1], bc(u1.y), a1);
                a1 = dot2(wzip[4 * m + 2], bc(u1.z), a1);
                a1 = dot2(wzip[4 * m + 3], bc(u1.w), a1);
            }
            red[q][0][i] = a0;
            red[q][1][i] = a1;
        }
        __syncthreads();  // B

        // ---- phase 5: z update ----
        if (tid < 512) {
            const int b = q;
            const float tmp = red[0][b][i] + red[1][b][i] + red[2][b][i] + red[3][b][i] + bzi_r;
            z_r = 0.99f * z_r + 0.01f * tmp;
            zl[b][i] = z_r;
            tzh[b][i] = (_Float16)fast_tanh(z_r);
            stp[(size_t)t * (BATCH * 512)] = z_r;
        }
        __syncthreads();  // C

        // ---- phase 7: signal & (tanh(h)@V) -> gl[b][r] ----
        {
            const int g = tid >> 6, l = tid & 63;
            const int b = g >> 3, r = g & 7;
            float zp = 0.f, hp = 0.f;
            #pragma unroll
            for (int m = 0; m < 4; ++m) {
                const int k = l + 64 * m;
                zp = fmaf(zl[b][k], wzo[r][k], zp);
                hp = fmaf(th[b][k], vt[r][k], hp);
            }
            #pragma unroll
            for (int off = 32; off >= 1; off >>= 1) {
                zp += __shfl_xor(zp, off);
                hp += __shfl_xor(hp, off);
            }
            if (l == 0) {
                const float sig = 1.f / (1.f + __expf(-(zp + bzo[r])));
                gl[b][r] = sig * hp;
            }
        }
        __syncthreads();  // D

        // ---- phase 9: h partial dots (U@g on q==0, W_in f16 slice all q) ----
        {
            float p0 = 0.f, p1 = 0.f;
            if (q == 0) {
                #pragma unroll
                for (int r = 0; r < RANK; ++r) {
                    const float u = ut[r][i];
                    p0 = fmaf(u, gl[0][r], p0);
                    p1 = fmaf(u, gl[1][r], p1);
                }
            }
            const uint4 u0 = *reinterpret_cast<const uint4*>(&sclh[0][q << 3]);
            const uint4 u1 = *reinterpret_cast<const uint4*>(&sclh[1][q << 3]);
            p0 = dot2(wip[0], bc(u0.x), p0);
            p0 = dot2(wip[1], bc(u0.y), p0);
            p0 = dot2(wip[2], bc(u0.z), p0);
            p0 = dot2(wip[3], bc(u0.w), p0);
            p1 = dot2(wip[0], bc(u1.x), p1);
            p1 = dot2(wip[1], bc(u1.y), p1);
            p1 = dot2(wip[2], bc(u1.z), p1);
            p1 = dot2(wip[3], bc(u1.w), p1);
            red[q][0][i] = p0;
            red[q][1][i] = p1;
        }
        __syncthreads();  // E

        // ---- phase 11: h update ----
        if (tid < 512) {
            const int b = q;
            const float tmp = red[0][b][i] + red[1][b][i] + red[2][b][i] + red[3][b][i] + bi_r;
            h_r = 0.9f * h_r + 0.1f * tmp;
            th[b][i] = fast_tanh(h_r);
            stp[(size_t)t * (BATCH * 512) + 256] = h_r;
        }
        // no barrier: next-iter phase 1 writes sclh (ordered by E w.r.t. the
        // phase-9 reads); barrier A orders th for next iter's phase 13'.
    }

    // ---- final out (t = T_STEPS-1) ----
    __syncthreads();
    {
        const int g = tid >> 6, l = tid & 63;
        float o0 = 0.f, o1 = 0.f;
        #pragma unroll
        for (int m = 0; m < 4; ++m) {
            const int k = l + 64 * m;
            const float w = wo[g][k];
            o0 = fmaf(th[0][k], w, o0);
            o1 = fmaf(th[1][k], w, o1);
        }
        #pragma unroll
        for (int off = 32; off >= 1; off >>= 1) {
            o0 += __shfl_xor(o0, off);
            o1 += __shfl_xor(o1, off);
        }
        if (l == 0) {
            out[((size_t)(T_STEPS - 1) * BATCH + b0) * 16 + g]     = o0 + bo[g];
            out[((size_t)(T_STEPS - 1) * BATCH + b0 + 1) * 16 + g] = o1 + bo[g];
        }
    }
}

extern "C" void kernel_launch(void* const* d_in, const int* in_sizes, int n_in,
                              void* d_out, int out_size, void* d_ws, size_t ws_size,
                              hipStream_t stream) {
    const float* s     = (const float*)d_in[0];
    const float* c     = (const float*)d_in[1];
    const float* W_zz  = (const float*)d_in[2];
    const float* Wz_in = (const float*)d_in[3];
    const float* bz_in = (const float*)d_in[4];
    const float* Wz_out= (const float*)d_in[5];
    const float* bz_out= (const float*)d_in[6];
    const float* U     = (const float*)d_in[7];
    const float* V     = (const float*)d_in[8];
    const float* W_in  = (const float*)d_in[9];
    const float* b_in  = (const float*)d_in[10];
    const float* W_out = (const float*)d_in[11];
    const float* b_out = (const float*)d_in[12];

    float* out    = (float*)d_out;
    float* states = out + (size_t)T_STEPS * BATCH * DY;

    hipLaunchKernelGGL(nmrnn_kernel, dim3(BATCH / 2), dim3(1024), 0, stream,
                       s, c, W_zz, Wz_in, bz_in, Wz_out, bz_out, U, V,
                       W_in, b_in, W_out, b_out, out, states);
}